// Round 17
// baseline (289.396 us; speedup 1.0000x reference)
//
#include <hip/hip_runtime.h>

typedef float f32x4 __attribute__((ext_vector_type(4)));
typedef float f32x16 __attribute__((ext_vector_type(16)));
typedef __bf16 bf16x8 __attribute__((ext_vector_type(8)));
typedef unsigned short u16;
typedef unsigned int u32;
typedef u16 u16x8 __attribute__((ext_vector_type(8)));
typedef u16 u16x4 __attribute__((ext_vector_type(4)));
typedef u32 u32x4 __attribute__((ext_vector_type(4)));

#define SCALE2F (0.044194173824159216f * 1.4426950408889634f)   // 1/sqrt(512) * log2(e)
#define UNSCALE (1.0f / SCALE2F)

__device__ __forceinline__ u16 f2bf(float x){ return __builtin_bit_cast(u16, (__bf16)x); }
__device__ __forceinline__ float bf2f(u16 h){ unsigned u = ((unsigned)h) << 16; return __builtin_bit_cast(float, u); }
// XOR swizzle within a 128B row: involution, bijective per 128B wrap
__device__ __forceinline__ int swz(int r, int byteInRow){ return (r*128 + byteInRow) ^ ((r & 7) << 4); }
// async global->LDS, 16B per lane; LDS dest must be wave-uniform base + lane*16
__device__ __forceinline__ void gload16(const void* g, void* l) {
  __builtin_amdgcn_global_load_lds(
      (const __attribute__((address_space(1))) void*)g,
      (__attribute__((address_space(3))) void*)l, 16, 0, 0);
}
__device__ __forceinline__ u32 cvtpk(float lo, float hi_) {
  u32 r;
  asm("v_cvt_pk_bf16_f32 %0, %1, %2" : "=v"(r) : "v"(lo), "v"(hi_));
  return r;
}
// v_permlane32_swap_b32: a' = {a.lo32, b.lo32}, b' = {a.hi32, b.hi32}
__device__ __forceinline__ void swap32(u32 &a, u32 &b) {
  asm("v_permlane32_swap_b32 %0, %1" : "+v"(a), "+v"(b));
}

#define MFMA(a,b,c)   __builtin_amdgcn_mfma_f32_16x16x32_bf16((a),(b),(c),0,0,0)
#define MFMA32(a,b,c) __builtin_amdgcn_mfma_f32_32x32x16_bf16((a),(b),(c),0,0,0)

// ---------------- weight prep: Wt[n][k] = bf16(W[k][n] * sc), 512x512 x4 ----------------
__global__ __launch_bounds__(256) void wprep_k(
    const float* __restrict__ W0, const float* __restrict__ W1,
    const float* __restrict__ W2, const float* __restrict__ W3,
    u16* __restrict__ wt)
{
  __shared__ float tile[64][68];
  const float* Ws[4] = {W0, W1, W2, W3};
  const float* W = Ws[blockIdx.z];
  const float sc = (blockIdx.z == 0) ? SCALE2F : 1.0f;   // fold softmax scale into Wq
  u16* out = wt + (size_t)blockIdx.z * 512 * 512;
  int k0 = blockIdx.x * 64, n0 = blockIdx.y * 64;
  int t = threadIdx.x;
  #pragma unroll
  for (int i = 0; i < 2; ++i) {
    int c = t + i*256; int r = c >> 3, k8 = c & 7;
    const float* src = W + (size_t)(k0 + r)*512 + n0 + k8*8;
    *(f32x4*)&tile[r][k8*8]     = *(const f32x4*)src;
    *(f32x4*)&tile[r][k8*8 + 4] = *(const f32x4*)(src + 4);
  }
  __syncthreads();
  #pragma unroll
  for (int i = 0; i < 2; ++i) {
    int c = t + i*256; int r = c >> 3, k8 = c & 7;
    u16x8 h;
    #pragma unroll
    for (int j = 0; j < 8; ++j) h[j] = f2bf(tile[k8*8 + j][r] * sc);
    *(u16x8*)(out + (size_t)(n0 + r)*512 + k0 + k8*8) = h;
  }
}

// ---------------- projections (r13 structure + XCD-grouped grid) ------------------------
__global__ __launch_bounds__(512) void proj2_k(
    const float* __restrict__ Qin, const float* __restrict__ Kin,
    const u16* __restrict__ wt,
    const float* __restrict__ bq, const float* __restrict__ bk, const float* __restrict__ bv,
    u16* __restrict__ qbuf, u16* __restrict__ kbuf, u16* __restrict__ vt)
{
  __shared__ __align__(16) u16 lA[2][64*64];     // 16KB
  __shared__ __align__(16) u16 lB0[2][128*64];   // 32KB
  __shared__ __align__(16) u16 lB1[2][128*64];   // 32KB  (used only by z=1)
  int j = blockIdx.x;
  int xcd = j & 7, s = j >> 3;          // s: 0..127
  int py = s & 3;
  int z  = (s >> 2) & 1;
  int px = (s >> 3) * 8 + xcd;
  const float* A     = z ? Kin : Qin;
  const u16*   Bt0   = wt + (size_t)(z ? 1 : 0) * 262144;
  const u16*   Bt1   = wt + (size_t)2 * 262144;
  const float* bias0 = z ? bk : bq;
  const float bscale = z ? 1.0f : SCALE2F;
  int row0 = px * 64, col0 = py * 128;
  int t = threadIdx.x, lane = t & 63, wid = t >> 6;
  int wr = wid >> 2, wc = wid & 3;
  int l15 = lane & 15, lg = lane >> 4;
  int ar = t >> 3, ak8 = t & 7;
  int br = t >> 3;
  int bsrc = ((t & 7) ^ (br & 7)) << 3;
  const float* Arow = A + (size_t)row0 * 512;
  const u16*   B0row = Bt0 + (size_t)col0 * 512;
  const u16*   B1row = Bt1 + (size_t)col0 * 512;

  f32x4 acc0[2][2] = {}, acc1[2][2] = {};

  #pragma unroll
  for (int i = 0; i < 2; ++i)
    gload16(B0row + (size_t)(br + i*64)*512 + bsrc, (char*)lB0[0] + i*8192 + t*16);
  if (z) {
    #pragma unroll
    for (int i = 0; i < 2; ++i)
      gload16(B1row + (size_t)(br + i*64)*512 + bsrc, (char*)lB1[0] + i*8192 + t*16);
  }
  {
    const float* src = Arow + (size_t)ar*512 + ak8*8;
    f32x4 x0 = *(const f32x4*)src;
    f32x4 x1 = *(const f32x4*)(src + 4);
    u16x8 h;
    #pragma unroll
    for (int jj = 0; jj < 4; ++jj) { h[jj] = f2bf(x0[jj]); h[jj+4] = f2bf(x1[jj]); }
    *(u16x8*)((char*)lA[0] + swz(ar, ak8*16)) = h;
  }
  __syncthreads();

  int cur = 0;
  for (int k0 = 0; k0 < 512; k0 += 64) {
    bool pf = (k0 + 64 < 512);
    f32x4 px0, px1;
    if (pf) {
      #pragma unroll
      for (int i = 0; i < 2; ++i)
        gload16(B0row + (size_t)(br + i*64)*512 + k0 + 64 + bsrc, (char*)lB0[cur^1] + i*8192 + t*16);
      if (z) {
        #pragma unroll
        for (int i = 0; i < 2; ++i)
          gload16(B1row + (size_t)(br + i*64)*512 + k0 + 64 + bsrc, (char*)lB1[cur^1] + i*8192 + t*16);
      }
      const float* src = Arow + (size_t)ar*512 + k0 + 64 + ak8*8;
      px0 = *(const f32x4*)src;
      px1 = *(const f32x4*)(src + 4);
    }
    const char* lAc = (const char*)lA[cur];
    const char* lB0c = (const char*)lB0[cur];
    const char* lB1c = (const char*)lB1[cur];
    #pragma unroll
    for (int ks = 0; ks < 2; ++ks) {
      bf16x8 af[2], b0f[2], b1f[2];
      #pragma unroll
      for (int m = 0; m < 2; ++m)
        af[m] = *(const bf16x8*)(lAc + swz(wr*32 + m*16 + l15, ks*64 + lg*16));
      #pragma unroll
      for (int n = 0; n < 2; ++n) {
        int rb = wc*32 + n*16 + l15;
        b0f[n] = *(const bf16x8*)(lB0c + swz(rb, ks*64 + lg*16));
        if (z) b1f[n] = *(const bf16x8*)(lB1c + swz(rb, ks*64 + lg*16));
      }
      #pragma unroll
      for (int m = 0; m < 2; ++m)
        #pragma unroll
        for (int n = 0; n < 2; ++n) {
          acc0[m][n] = MFMA(af[m], b0f[n], acc0[m][n]);
          if (z) acc1[m][n] = MFMA(af[m], b1f[n], acc1[m][n]);
        }
    }
    if (pf) {
      u16x8 h;
      #pragma unroll
      for (int jj = 0; jj < 4; ++jj) { h[jj] = f2bf(px0[jj]); h[jj+4] = f2bf(px1[jj]); }
      *(u16x8*)((char*)lA[cur^1] + swz(ar, ak8*16)) = h;
    }
    __syncthreads();
    cur ^= 1;
  }

  u16* out0 = z ? kbuf : qbuf;
  #pragma unroll
  for (int m = 0; m < 2; ++m) {
    int rowg = row0 + wr*32 + m*16 + lg*4;
    #pragma unroll
    for (int n = 0; n < 2; ++n) {
      int colg = col0 + wc*32 + n*16 + l15;
      float bvv = bias0[colg] * bscale;
      #pragma unroll
      for (int r = 0; r < 4; ++r)
        out0[(size_t)(rowg + r)*512 + colg] = f2bf(acc0[m][n][r] + bvv);
    }
  }
  if (z) {
    #pragma unroll
    for (int m = 0; m < 2; ++m) {
      int rowg = row0 + wr*32 + m*16 + lg*4;
      int b = rowg >> 11, ntok = rowg & 2047;
      #pragma unroll
      for (int n = 0; n < 2; ++n) {
        int colg = col0 + wc*32 + n*16 + l15;
        float bvv = bv[colg];
        u16x4 hv;
        #pragma unroll
        for (int r = 0; r < 4; ++r) hv[r] = f2bf(acc1[m][n][r] + bvv);
        *(u16x4*)(vt + ((size_t)b*512 + colg)*2048 + ntok) = hv;
      }
    }
  }
}

// ---------------- flash attention: 16 waves = 4 q-waves x 4 KV-quarters, q=64/wave ------
// K/V fragments shared across BOTH q-groups of a wave (halves LDS reads/FLOP vs r16);
// 4 waves/SIMD needs regs<=128: mk_pb restructured so exp values die into cvtpk
// immediately (peak 4 live p's). In-block 4-way combine via bf16 partials in (dead)
// tile LDS -- no global combine traffic.
__device__ __forceinline__ void mk_pb(const f32x16& s, float& ps, bf16x8& f0, bf16x8& f1) {
  u32 a0, a1, b0, b1;
  float t0, t1;
  {
    float e0 = __builtin_amdgcn_exp2f(s[0]), e1 = __builtin_amdgcn_exp2f(s[1]);
    float e2 = __builtin_amdgcn_exp2f(s[2]), e3 = __builtin_amdgcn_exp2f(s[3]);
    a0 = cvtpk(e0, e1); a1 = cvtpk(e2, e3);
    t0 = (e0 + e1) + (e2 + e3);
  }
  {
    float e0 = __builtin_amdgcn_exp2f(s[4]), e1 = __builtin_amdgcn_exp2f(s[5]);
    float e2 = __builtin_amdgcn_exp2f(s[6]), e3 = __builtin_amdgcn_exp2f(s[7]);
    b0 = cvtpk(e0, e1); b1 = cvtpk(e2, e3);
    t0 += (e0 + e1) + (e2 + e3);
  }
  swap32(a0, b0); swap32(a1, b1);
  u32x4 w0 = {a0, a1, b0, b1};
  f0 = __builtin_bit_cast(bf16x8, w0);
  u32 a2, a3, b2, b3;
  {
    float e0 = __builtin_amdgcn_exp2f(s[8]), e1 = __builtin_amdgcn_exp2f(s[9]);
    float e2 = __builtin_amdgcn_exp2f(s[10]), e3 = __builtin_amdgcn_exp2f(s[11]);
    a2 = cvtpk(e0, e1); a3 = cvtpk(e2, e3);
    t1 = (e0 + e1) + (e2 + e3);
  }
  {
    float e0 = __builtin_amdgcn_exp2f(s[12]), e1 = __builtin_amdgcn_exp2f(s[13]);
    float e2 = __builtin_amdgcn_exp2f(s[14]), e3 = __builtin_amdgcn_exp2f(s[15]);
    b2 = cvtpk(e0, e1); b3 = cvtpk(e2, e3);
    t1 += (e0 + e1) + (e2 + e3);
  }
  swap32(a2, b2); swap32(a3, b3);
  u32x4 w1 = {a2, a3, b2, b3};
  f1 = __builtin_bit_cast(bf16x8, w1);
  ps += t0 + t1;
}

__global__ __launch_bounds__(1024, 4) void attn_k(
    const u16* __restrict__ qb, const u16* __restrict__ kb,
    const u16* __restrict__ vt, u16* __restrict__ ob)
{
  // tiles: lK quarters 0..3 x dbuf (64KB) | lV same (64KB). Combine overlays this space.
  __shared__ __align__(16) char smem[131072];

  int t = threadIdx.x, lane = t & 63, wid = t >> 6;
  // XCD-aware decode (bijective over 256): all 8 q-blocks of a (b,h) share an XCD
  int j = blockIdx.x;
  int xcd = j & 7, s = j >> 3;
  int qx = s & 7;
  int bh = ((s >> 3) << 3) | xcd;
  int b = bh >> 3, h = bh & 7;
  int qw = wid & 3, qtr = wid >> 2;            // q-wave 0..3, KV-quarter 0..3
  int q0 = qx * 256 + qw * 64;                 // this wave's 64 q-rows (A: +0, B: +32)
  int l31 = lane & 31, hi = lane >> 5;

  const u16* kbase = kb + ((size_t)b*2048)*512 + h*64;
  const u16* vbase = vt + ((size_t)b*512 + h*64)*2048;

  // staging: 1024 thr x 16B = 16KB/line; each line covers a quarter-pair
  int qt2 = t >> 9, tl = t & 511;
  int sr = tl >> 3;                                  // 0..63
  int ssrc = ((tl & 7) ^ (sr & 7)) << 3;             // inverse-swizzled src col (elements)

#define LK(q_, b_) (smem + ((q_)*2 + (b_))*8192)
#define LV(q_, b_) (smem + 65536 + ((q_)*2 + (b_))*8192)
#define STAGE(buf, off)                                                                      \
  gload16(kbase + (size_t)(qt2*512 + (off) + sr)*512 + ssrc,      LK(qt2, buf) + tl*16);     \
  gload16(kbase + (size_t)((2+qt2)*512 + (off) + sr)*512 + ssrc,  LK(2+qt2, buf) + tl*16);   \
  gload16(vbase + (size_t)sr*2048 + qt2*512 + (off) + ssrc,       LV(qt2, buf) + tl*16);     \
  gload16(vbase + (size_t)sr*2048 + (2+qt2)*512 + (off) + ssrc,   LV(2+qt2, buf) + tl*16);

  // Q as B-operand: col q = l31, k = ks*16 + hi*8 + j ; groups A (q0) and B (q0+32)
  bf16x8 aqA[4], aqB[4];
  {
    const u16* qpA = qb + ((size_t)(b*2048 + q0 + l31))*512 + h*64 + hi*8;
    const u16* qpB = qpA + (size_t)32*512;
    #pragma unroll
    for (int ks = 0; ks < 4; ++ks) {
      aqA[ks] = *(const bf16x8*)(qpA + ks*16);
      aqB[ks] = *(const bf16x8*)(qpB + ks*16);
    }
  }

  f32x16 accA[2] = {}, accB[2] = {};
  float psA = 0.0f, psB = 0.0f;

  STAGE(0, 0);
  __syncthreads();

  int cur = 0;
  for (int i = 0; i < 8; ++i) {
    if (i + 1 < 8) { STAGE(cur^1, (i+1)*64); }
    const char* lKc = (const char*)LK(qtr, cur);
    const char* lVc = (const char*)LV(qtr, cur);
    bf16x8 pbA[4], pbB[4];
    #pragma unroll
    for (int n = 0; n < 2; ++n) {
      f32x16 s0 = {}, s1 = {};
      #pragma unroll
      for (int ks = 0; ks < 4; ++ks) {
        bf16x8 kf = *(const bf16x8*)(lKc + swz(n*32 + l31, ks*32 + hi*16));
        s0 = MFMA32(kf, aqA[ks], s0);          // K-frag read once, used for both q-groups
        s1 = MFMA32(kf, aqB[ks], s1);
      }
      mk_pb(s0, psA, pbA[2*n], pbA[2*n+1]);
      mk_pb(s1, psB, pbB[2*n], pbB[2*n+1]);
    }
    #pragma unroll
    for (int m = 0; m < 2; ++m)
      #pragma unroll
      for (int ks = 0; ks < 4; ++ks) {
        bf16x8 vf = *(const bf16x8*)(lVc + swz(m*32 + l31, ks*32 + hi*16));
        accA[m] = MFMA32(vf, pbA[ks], accA[m]);  // V-frag read once, used twice
        accB[m] = MFMA32(vf, pbB[ks], accB[m]);
      }
    __syncthreads();
    cur ^= 1;
  }
#undef STAGE

  // ---- in-block 4-way combine (overlays the now-dead tile LDS) ----
  psA += __shfl_xor(psA, 32, 64);
  psB += __shfl_xor(psB, 32, 64);
  u16*   cbh = (u16*)smem;                 // 48 units x 2KB bf16 partials (96KB)
  float* cps = (float*)(smem + 98304);     // 24 x 32 f32 partial sums (3KB)
  if (qtr > 0) {
    int ub = (qw*3 + (qtr-1)) * 4;         // units: A.m0, A.m1, B.m0, B.m1
    #pragma unroll
    for (int m = 0; m < 2; ++m) {
      u16x8 h0, h1, g0v, g1v;
      #pragma unroll
      for (int e = 0; e < 8; ++e) {
        h0[e]  = f2bf(accA[m][e]);
        h1[e]  = f2bf(accA[m][8+e]);
        g0v[e] = f2bf(accB[m][e]);
        g1v[e] = f2bf(accB[m][8+e]);
      }
      *(u16x8*)(cbh + (ub+m)*1024   + lane*16)     = h0;
      *(u16x8*)(cbh + (ub+m)*1024   + lane*16 + 8) = h1;
      *(u16x8*)(cbh + (ub+2+m)*1024 + lane*16)     = g0v;
      *(u16x8*)(cbh + (ub+2+m)*1024 + lane*16 + 8) = g1v;
    }
    if (hi == 0) {
      cps[((qw*3 + (qtr-1))*2 + 0)*32 + l31] = psA;
      cps[((qw*3 + (qtr-1))*2 + 1)*32 + l31] = psB;
    }
  }
  __syncthreads();
  if (qtr == 0) {
    #pragma unroll
    for (int qq = 0; qq < 3; ++qq) {
      int ub = (qw*3 + qq) * 4;
      #pragma unroll
      for (int m = 0; m < 2; ++m) {
        u16x8 h0  = *(const u16x8*)(cbh + (ub+m)*1024   + lane*16);
        u16x8 h1  = *(const u16x8*)(cbh + (ub+m)*1024   + lane*16 + 8);
        u16x8 g0v = *(const u16x8*)(cbh + (ub+2+m)*1024 + lane*16);
        u16x8 g1v = *(const u16x8*)(cbh + (ub+2+m)*1024 + lane*16 + 8);
        #pragma unroll
        for (int e = 0; e < 8; ++e) {
          accA[m][e]   += bf2f(h0[e]);
          accA[m][8+e] += bf2f(h1[e]);
          accB[m][e]   += bf2f(g0v[e]);
          accB[m][8+e] += bf2f(g1v[e]);
        }
      }
      psA += cps[((qw*3 + qq)*2 + 0)*32 + l31];
      psB += cps[((qw*3 + qq)*2 + 1)*32 + l31];
    }
    float invA = 1.0f / psA, invB = 1.0f / psB;
    u16* oA = ob + ((size_t)(b*2048 + q0 + l31))*512 + h*64;
    u16* oB = oA + (size_t)32*512;
    const u16* qrA = qb + ((size_t)(b*2048 + q0 + l31))*512 + h*64;
    const u16* qrB = qrA + (size_t)32*512;
    #pragma unroll
    for (int m = 0; m < 2; ++m)
      #pragma unroll
      for (int rq = 0; rq < 4; ++rq) {
        u16x4 qa = *(const u16x4*)(qrA + m*32 + rq*8 + hi*4);
        u16x4 qv = *(const u16x4*)(qrB + m*32 + rq*8 + hi*4);
        u16x4 o4a, o4b;
        #pragma unroll
        for (int e = 0; e < 4; ++e) {
          o4a[e] = f2bf(accA[m][rq*4 + e]*invA + bf2f(qa[e])*UNSCALE);
          o4b[e] = f2bf(accB[m][rq*4 + e]*invB + bf2f(qv[e])*UNSCALE);
        }
        *(u16x4*)(oA + m*32 + rq*8 + hi*4) = o4a;
        *(u16x4*)(oB + m*32 + rq*8 + hi*4) = o4b;
      }
  }
#undef LK
#undef LV
}

// ---------------- fused tail: LN0 (on-the-fly) -> Wo GEMM + ReLU + residual -> LN1 ------
__global__ __launch_bounds__(512) void tail_k(
    const u16* __restrict__ ob, const u16* __restrict__ Bt,
    const float* __restrict__ bo,
    const float* __restrict__ g0, const float* __restrict__ b0,
    const float* __restrict__ g1, const float* __restrict__ b1,
    float* __restrict__ out)
{
  __shared__ __align__(16) u16 lA[2][32*64];     // 4KB each
  __shared__ __align__(16) u16 lB[2][512*64];    // 64KB each
  __shared__ float mu0[32], rs0[32], mu1[32], rs1[32];
  __shared__ float ps1[32][8], ss1[32][8];

  int row0 = blockIdx.x * 32;
  int t = threadIdx.x, lane = t & 63, wid = t >> 6;
  int l15 = lane & 15, lg = lane >> 4;

  {
    int r = t >> 4, c0 = (t & 15) * 32;
    const u16* xp = ob + (size_t)(row0 + r)*512 + c0;
    float s = 0.0f, ss = 0.0f;
    #pragma unroll
    for (int j = 0; j < 4; ++j) {
      u16x8 v = *(const u16x8*)(xp + j*8);
      #pragma unroll
      for (int e = 0; e < 8; ++e) { float f = bf2f(v[e]); s += f; ss += f*f; }
    }
    #pragma unroll
    for (int m = 1; m < 16; m <<= 1) { s += __shfl_xor(s, m, 64); ss += __shfl_xor(ss, m, 64); }
    if ((t & 15) == 0) {
      float mu = s * (1.0f/512.0f);
      float var = ss * (1.0f/512.0f) - mu*mu;
      mu0[r] = mu; rs0[r] = rsqrtf(var + 1e-5f);
    }
  }
  __syncthreads();

  int ar = t >> 3, ak8 = t & 7;
  int br = t >> 3;
  int bsrc = ((t & 7) ^ (br & 7)) << 3;

  auto stageA = [&](int buf, int k0) {
    if (t < 256) {
      u16x8 x = *(const u16x8*)(ob + (size_t)(row0 + ar)*512 + k0 + ak8*8);
      f32x4 gv0 = *(const f32x4*)(g0 + k0 + ak8*8);
      f32x4 gv1 = *(const f32x4*)(g0 + k0 + ak8*8 + 4);
      f32x4 bv0 = *(const f32x4*)(b0 + k0 + ak8*8);
      f32x4 bv1 = *(const f32x4*)(b0 + k0 + ak8*8 + 4);
      float mu = mu0[ar], rs = rs0[ar];
      u16x8 h;
      #pragma unroll
      for (int j = 0; j < 4; ++j) {
        h[j]   = f2bf((bf2f(x[j])   - mu)*rs*gv0[j] + bv0[j]);
        h[j+4] = f2bf((bf2f(x[j+4]) - mu)*rs*gv1[j] + bv1[j]);
      }
      *(u16x8*)((char*)lA[buf] + swz(ar, ak8*16)) = h;
    }
  };

  #pragma unroll
  for (int i = 0; i < 8; ++i)
    gload16(Bt + (size_t)(br + i*64)*512 + bsrc, (char*)lB[0] + i*8192 + t*16);
  stageA(0, 0);
  __syncthreads();

  f32x4 acc[2][4] = {};
  int cur = 0;
  for (int k0 = 0; k0 < 512; k0 += 64) {
    if (k0 + 64 < 512) {
      #pragma unroll
      for (int i = 0; i < 8; ++i)
        gload16(Bt + (size_t)(br + i*64)*512 + k0 + 64 + bsrc, (char*)lB[cur^1] + i*8192 + t*16);
      stageA(cur^1, k0 + 64);
    }
    const char* lAc = (const char*)lA[cur];
    const char* lBc = (const char*)lB[cur];
    #pragma unroll
    for (int ks = 0; ks < 2; ++ks) {
      bf16x8 af[2], bfv[4];
      #pragma unroll
      for (int m = 0; m < 2; ++m)
        af[m] = *(const bf16x8*)(lAc + swz(m*16 + l15, ks*64 + lg*16));
      #pragma unroll
      for (int n = 0; n < 4; ++n)
        bfv[n] = *(const bf16x8*)(lBc + swz(wid*64 + n*16 + l15, ks*64 + lg*16));
      #pragma unroll
      for (int m = 0; m < 2; ++m)
        #pragma unroll
        for (int n = 0; n < 4; ++n)
          acc[m][n] = MFMA(af[m], bfv[n], acc[m][n]);
    }
    __syncthreads();
    cur ^= 1;
  }

  float Gv[2][4][4];
  float sp[2][4] = {}, ssp[2][4] = {};
  #pragma unroll
  for (int n = 0; n < 4; ++n) {
    int colg = wid*64 + n*16 + l15;
    float bov = bo[colg];
    float g0c = g0[colg], b0c = b0[colg];
    #pragma unroll
    for (int m = 0; m < 2; ++m) {
      #pragma unroll
      for (int rr = 0; rr < 4; ++rr) {
        int rit = m*16 + lg*4 + rr;
        float H = (bf2f(ob[(size_t)(row0 + rit)*512 + colg]) - mu0[rit])*rs0[rit]*g0c + b0c;
        float G = H + fmaxf(acc[m][n][rr] + bov, 0.0f);
        Gv[m][n][rr] = G;
        sp[m][rr] += G;
        ssp[m][rr] += G*G;
      }
    }
  }
  #pragma unroll
  for (int msk = 1; msk < 16; msk <<= 1)
    #pragma unroll
    for (int m = 0; m < 2; ++m)
      #pragma unroll
      for (int rr = 0; rr < 4; ++rr) {
        sp[m][rr]  += __shfl_xor(sp[m][rr],  msk, 64);
        ssp[m][rr] += __shfl_xor(ssp[m][rr], msk, 64);
      }
  if (l15 == 0) {
    #pragma unroll
    for (int m = 0; m < 2; ++m)
      #pragma unroll
      for (int rr = 0; rr < 4; ++rr) {
        int rit = m*16 + lg*4 + rr;
        ps1[rit][wid] = sp[m][rr];
        ss1[rit][wid] = ssp[m][rr];
      }
  }
  __syncthreads();
  if (t < 32) {
    float s = 0.0f, ss = 0.0f;
    #pragma unroll
    for (int w = 0; w < 8; ++w) { s += ps1[t][w]; ss += ss1[t][w]; }
    float mu = s * (1.0f/512.0f);
    float var = ss * (1.0f/512.0f) - mu*mu;
    mu1[t] = mu; rs1[t] = rsqrtf(var + 1e-5f);
  }
  __syncthreads();
  #pragma unroll
  for (int n = 0; n < 4; ++n) {
    int colg = wid*64 + n*16 + l15;
    float g1c = g1[colg], b1c = b1[colg];
    #pragma unroll
    for (int m = 0; m < 2; ++m)
      #pragma unroll
      for (int rr = 0; rr < 4; ++rr) {
        int rit = m*16 + lg*4 + rr;
        out[(size_t)(row0 + rit)*512 + colg] =
            (Gv[m][n][rr] - mu1[rit])*rs1[rit]*g1c + b1c;
      }
  }
}

extern "C" void kernel_launch(void* const* d_in, const int* in_sizes, int n_in,
                              void* d_out, int out_size, void* d_ws, size_t ws_size,
                              hipStream_t stream)
{
  const float* Q   = (const float*)d_in[0];
  const float* K   = (const float*)d_in[1];
  const float* Wq  = (const float*)d_in[2];
  const float* bq  = (const float*)d_in[3];
  const float* Wk  = (const float*)d_in[4];
  const float* bk  = (const float*)d_in[5];
  const float* Wv  = (const float*)d_in[6];
  const float* bv  = (const float*)d_in[7];
  const float* Wo  = (const float*)d_in[8];
  const float* bo  = (const float*)d_in[9];
  const float* g0  = (const float*)d_in[10];
  const float* b0  = (const float*)d_in[11];
  const float* g1  = (const float*)d_in[12];
  const float* b1  = (const float*)d_in[13];

  char* ws = (char*)d_ws;
  u16*   wt    = (u16*)(ws + 0);
  u16*   qbuf  = (u16*)(ws + (2u<<20));
  u16*   kbuf  = (u16*)(ws + (10u<<20));
  u16*   vt    = (u16*)(ws + (18u<<20));
  u16*   ob    = (u16*)(ws + (26u<<20));

  // 1. weight transpose+convert (Wq/bq scaled by 1/sqrt(512)*log2e)
  wprep_k<<<dim3(8, 8, 4), 256, 0, stream>>>(Wq, Wk, Wv, Wo, wt);
  // 2. projections: fused K+V (K staged once), V pre-transposed; XCD-grouped grid
  proj2_k<<<1024, 512, 0, stream>>>(Q, K, wt, bq, bk, bv, qbuf, kbuf, vt);
  // 3. attention: 16 waves/block, q=64/wave, 4 KV-quarters, in-block combine -> ob
  attn_k<<<256, 1024, 0, stream>>>(qbuf, kbuf, vt, ob);
  // 4. fused tail: LN0 -> Wo GEMM + ReLU + residual -> LN1 -> out (fp32)
  tail_k<<<256, 512, 0, stream>>>(ob, wt + 3*262144, bo, g0, b0, g1, b1, (float*)d_out);
}

// Round 18
// 94.369 us; speedup vs baseline: 3.0666x; 3.0666x over previous
//
#include <hip/hip_runtime.h>

typedef float f32x4 __attribute__((ext_vector_type(4)));
typedef float f32x16 __attribute__((ext_vector_type(16)));
typedef __bf16 bf16x8 __attribute__((ext_vector_type(8)));
typedef unsigned short u16;
typedef unsigned int u32;
typedef u16 u16x8 __attribute__((ext_vector_type(8)));
typedef u16 u16x4 __attribute__((ext_vector_type(4)));
typedef u32 u32x4 __attribute__((ext_vector_type(4)));

#define SCALE2F (0.044194173824159216f * 1.4426950408889634f)   // 1/sqrt(512) * log2(e)
#define UNSCALE (1.0f / SCALE2F)

__device__ __forceinline__ u16 f2bf(float x){ return __builtin_bit_cast(u16, (__bf16)x); }
__device__ __forceinline__ float bf2f(u16 h){ unsigned u = ((unsigned)h) << 16; return __builtin_bit_cast(float, u); }
// XOR swizzle within a 128B row: involution, bijective per 128B wrap
__device__ __forceinline__ int swz(int r, int byteInRow){ return (r*128 + byteInRow) ^ ((r & 7) << 4); }
// async global->LDS, 16B per lane; LDS dest must be wave-uniform base + lane*16
__device__ __forceinline__ void gload16(const void* g, void* l) {
  __builtin_amdgcn_global_load_lds(
      (const __attribute__((address_space(1))) void*)g,
      (__attribute__((address_space(3))) void*)l, 16, 0, 0);
}
__device__ __forceinline__ u32 cvtpk(float lo, float hi_) {
  u32 r;
  asm("v_cvt_pk_bf16_f32 %0, %1, %2" : "=v"(r) : "v"(lo), "v"(hi_));
  return r;
}
// v_permlane32_swap_b32: a' = {a.lo32, b.lo32}, b' = {a.hi32, b.hi32}
__device__ __forceinline__ void swap32(u32 &a, u32 &b) {
  asm("v_permlane32_swap_b32 %0, %1" : "+v"(a), "+v"(b));
}

#define MFMA(a,b,c)   __builtin_amdgcn_mfma_f32_16x16x32_bf16((a),(b),(c),0,0,0)
#define MFMA32(a,b,c) __builtin_amdgcn_mfma_f32_32x32x16_bf16((a),(b),(c),0,0,0)

// ---------------- weight prep: Wt[n][k] = bf16(W[k][n] * sc), 512x512 x4 ----------------
__global__ __launch_bounds__(256) void wprep_k(
    const float* __restrict__ W0, const float* __restrict__ W1,
    const float* __restrict__ W2, const float* __restrict__ W3,
    u16* __restrict__ wt)
{
  __shared__ float tile[64][68];
  const float* Ws[4] = {W0, W1, W2, W3};
  const float* W = Ws[blockIdx.z];
  const float sc = (blockIdx.z == 0) ? SCALE2F : 1.0f;   // fold softmax scale into Wq
  u16* out = wt + (size_t)blockIdx.z * 512 * 512;
  int k0 = blockIdx.x * 64, n0 = blockIdx.y * 64;
  int t = threadIdx.x;
  #pragma unroll
  for (int i = 0; i < 2; ++i) {
    int c = t + i*256; int r = c >> 3, k8 = c & 7;
    const float* src = W + (size_t)(k0 + r)*512 + n0 + k8*8;
    *(f32x4*)&tile[r][k8*8]     = *(const f32x4*)src;
    *(f32x4*)&tile[r][k8*8 + 4] = *(const f32x4*)(src + 4);
  }
  __syncthreads();
  #pragma unroll
  for (int i = 0; i < 2; ++i) {
    int c = t + i*256; int r = c >> 3, k8 = c & 7;
    u16x8 h;
    #pragma unroll
    for (int j = 0; j < 8; ++j) h[j] = f2bf(tile[k8*8 + j][r] * sc);
    *(u16x8*)(out + (size_t)(n0 + r)*512 + k0 + k8*8) = h;
  }
}

// ---------------- projections (fused K+V, XCD-grouped grid; r16 verified) ---------------
__global__ __launch_bounds__(512) void proj2_k(
    const float* __restrict__ Qin, const float* __restrict__ Kin,
    const u16* __restrict__ wt,
    const float* __restrict__ bq, const float* __restrict__ bk, const float* __restrict__ bv,
    u16* __restrict__ qbuf, u16* __restrict__ kbuf, u16* __restrict__ vt)
{
  __shared__ __align__(16) u16 lA[2][64*64];     // 16KB
  __shared__ __align__(16) u16 lB0[2][128*64];   // 32KB
  __shared__ __align__(16) u16 lB1[2][128*64];   // 32KB  (used only by z=1)
  int j = blockIdx.x;
  int xcd = j & 7, s = j >> 3;          // s: 0..127
  int py = s & 3;
  int z  = (s >> 2) & 1;
  int px = (s >> 3) * 8 + xcd;
  const float* A     = z ? Kin : Qin;
  const u16*   Bt0   = wt + (size_t)(z ? 1 : 0) * 262144;
  const u16*   Bt1   = wt + (size_t)2 * 262144;
  const float* bias0 = z ? bk : bq;
  const float bscale = z ? 1.0f : SCALE2F;
  int row0 = px * 64, col0 = py * 128;
  int t = threadIdx.x, lane = t & 63, wid = t >> 6;
  int wr = wid >> 2, wc = wid & 3;
  int l15 = lane & 15, lg = lane >> 4;
  int ar = t >> 3, ak8 = t & 7;
  int br = t >> 3;
  int bsrc = ((t & 7) ^ (br & 7)) << 3;
  const float* Arow = A + (size_t)row0 * 512;
  const u16*   B0row = Bt0 + (size_t)col0 * 512;
  const u16*   B1row = Bt1 + (size_t)col0 * 512;

  f32x4 acc0[2][2] = {}, acc1[2][2] = {};

  #pragma unroll
  for (int i = 0; i < 2; ++i)
    gload16(B0row + (size_t)(br + i*64)*512 + bsrc, (char*)lB0[0] + i*8192 + t*16);
  if (z) {
    #pragma unroll
    for (int i = 0; i < 2; ++i)
      gload16(B1row + (size_t)(br + i*64)*512 + bsrc, (char*)lB1[0] + i*8192 + t*16);
  }
  {
    const float* src = Arow + (size_t)ar*512 + ak8*8;
    f32x4 x0 = *(const f32x4*)src;
    f32x4 x1 = *(const f32x4*)(src + 4);
    u16x8 h;
    #pragma unroll
    for (int jj = 0; jj < 4; ++jj) { h[jj] = f2bf(x0[jj]); h[jj+4] = f2bf(x1[jj]); }
    *(u16x8*)((char*)lA[0] + swz(ar, ak8*16)) = h;
  }
  __syncthreads();

  int cur = 0;
  for (int k0 = 0; k0 < 512; k0 += 64) {
    bool pf = (k0 + 64 < 512);
    f32x4 px0, px1;
    if (pf) {
      #pragma unroll
      for (int i = 0; i < 2; ++i)
        gload16(B0row + (size_t)(br + i*64)*512 + k0 + 64 + bsrc, (char*)lB0[cur^1] + i*8192 + t*16);
      if (z) {
        #pragma unroll
        for (int i = 0; i < 2; ++i)
          gload16(B1row + (size_t)(br + i*64)*512 + k0 + 64 + bsrc, (char*)lB1[cur^1] + i*8192 + t*16);
      }
      const float* src = Arow + (size_t)ar*512 + k0 + 64 + ak8*8;
      px0 = *(const f32x4*)src;
      px1 = *(const f32x4*)(src + 4);
    }
    const char* lAc = (const char*)lA[cur];
    const char* lB0c = (const char*)lB0[cur];
    const char* lB1c = (const char*)lB1[cur];
    #pragma unroll
    for (int ks = 0; ks < 2; ++ks) {
      bf16x8 af[2], b0f[2], b1f[2];
      #pragma unroll
      for (int m = 0; m < 2; ++m)
        af[m] = *(const bf16x8*)(lAc + swz(wr*32 + m*16 + l15, ks*64 + lg*16));
      #pragma unroll
      for (int n = 0; n < 2; ++n) {
        int rb = wc*32 + n*16 + l15;
        b0f[n] = *(const bf16x8*)(lB0c + swz(rb, ks*64 + lg*16));
        if (z) b1f[n] = *(const bf16x8*)(lB1c + swz(rb, ks*64 + lg*16));
      }
      #pragma unroll
      for (int m = 0; m < 2; ++m)
        #pragma unroll
        for (int n = 0; n < 2; ++n) {
          acc0[m][n] = MFMA(af[m], b0f[n], acc0[m][n]);
          if (z) acc1[m][n] = MFMA(af[m], b1f[n], acc1[m][n]);
        }
    }
    if (pf) {
      u16x8 h;
      #pragma unroll
      for (int jj = 0; jj < 4; ++jj) { h[jj] = f2bf(px0[jj]); h[jj+4] = f2bf(px1[jj]); }
      *(u16x8*)((char*)lA[cur^1] + swz(ar, ak8*16)) = h;
    }
    __syncthreads();
    cur ^= 1;
  }

  u16* out0 = z ? kbuf : qbuf;
  #pragma unroll
  for (int m = 0; m < 2; ++m) {
    int rowg = row0 + wr*32 + m*16 + lg*4;
    #pragma unroll
    for (int n = 0; n < 2; ++n) {
      int colg = col0 + wc*32 + n*16 + l15;
      float bvv = bias0[colg] * bscale;
      #pragma unroll
      for (int r = 0; r < 4; ++r)
        out0[(size_t)(rowg + r)*512 + colg] = f2bf(acc0[m][n][r] + bvv);
    }
  }
  if (z) {
    #pragma unroll
    for (int m = 0; m < 2; ++m) {
      int rowg = row0 + wr*32 + m*16 + lg*4;
      int b = rowg >> 11, ntok = rowg & 2047;
      #pragma unroll
      for (int n = 0; n < 2; ++n) {
        int colg = col0 + wc*32 + n*16 + l15;
        float bvv = bv[colg];
        u16x4 hv;
        #pragma unroll
        for (int r = 0; r < 4; ++r) hv[r] = f2bf(acc1[m][n][r] + bvv);
        *(u16x4*)(vt + ((size_t)b*512 + colg)*2048 + ntok) = hv;
      }
    }
  }
}

// ---------------- flash attention: 8 waves = 4 q-waves x 2 KV-halves, in-block combine --
// (r16 verified: 49 us, VGPR 64 no-spill, FETCH 12.8 MB with XCD decode.)
// NOTE: q=64-sharing at 4 waves/SIMD is register-infeasible (r8/r17: ~160-reg working
// set vs 128 cap -> 600+ MB spill). q=32@64regs and q=64@2waves both land at ~49 us.
__device__ __forceinline__ void mk_pb(const f32x16& s, float& ps, bf16x8& f0, bf16x8& f1) {
  float p[16];
  #pragma unroll
  for (int r = 0; r < 16; ++r) p[r] = __builtin_amdgcn_exp2f(s[r]);
  float t0 = (p[0] + p[1])  + (p[2] + p[3]);
  float t1 = (p[4] + p[5])  + (p[6] + p[7]);
  float t2 = (p[8] + p[9])  + (p[10] + p[11]);
  float t3 = (p[12] + p[13]) + (p[14] + p[15]);
  ps += (t0 + t1) + (t2 + t3);
  u32 a0 = cvtpk(p[0],  p[1]),  b0 = cvtpk(p[4],  p[5]);
  u32 a1 = cvtpk(p[2],  p[3]),  b1 = cvtpk(p[6],  p[7]);
  swap32(a0, b0); swap32(a1, b1);
  u32 a2 = cvtpk(p[8],  p[9]),  b2 = cvtpk(p[12], p[13]);
  u32 a3 = cvtpk(p[10], p[11]), b3 = cvtpk(p[14], p[15]);
  swap32(a2, b2); swap32(a3, b3);
  u32x4 w0 = {a0, a1, b0, b1};
  u32x4 w1 = {a2, a3, b2, b3};
  f0 = __builtin_bit_cast(bf16x8, w0);
  f1 = __builtin_bit_cast(bf16x8, w1);
}

__global__ __launch_bounds__(512, 4) void attn_k(
    const u16* __restrict__ qb, const u16* __restrict__ kb,
    const u16* __restrict__ vt, u16* __restrict__ ob)
{
  __shared__ __align__(16) char smem[65536];   // lK: 4x8KB | lV: 4x8KB; combine reuses lK

  int t = threadIdx.x, lane = t & 63, wid = t >> 6;
  // XCD-aware decode of 1D block id (bijective over 512)
  int j = blockIdx.x;
  int xcd = j & 7, slot = j >> 3;
  int qx = slot & 15;
  int bh = ((slot >> 4) << 3) | xcd;
  int b = bh >> 3, h = bh & 7;
  int half = wid >> 2;                         // KV half (0: 0-1023, 1: 1024-2047)
  int qw = wid & 3;
  int q0 = qx * 128 + qw * 32;                 // 4 q-waves x 32 rows
  int l31 = lane & 31, hi = lane >> 5;

  const u16* kbase = kb + ((size_t)b*2048)*512 + h*64;
  const u16* vbase = vt + ((size_t)b*512 + h*64)*2048;

  int sr = t >> 3;                                   // 0..63
  int ssrc = ((t & 7) ^ (sr & 7)) << 3;              // inverse-swizzled src col (elements)

#define LKB(hf, bf) (smem + ((hf)*2 + (bf))*8192)
#define LVB(hf, bf) (smem + 32768 + ((hf)*2 + (bf))*8192)
#define STAGE(buf, off)                                                           \
  gload16(kbase + (size_t)((off) + sr)*512 + ssrc,        LKB(0,buf) + t*16);     \
  gload16(kbase + (size_t)((off) + 1024 + sr)*512 + ssrc, LKB(1,buf) + t*16);     \
  gload16(vbase + (size_t)sr*2048 + (off) + ssrc,         LVB(0,buf) + t*16);     \
  gload16(vbase + (size_t)sr*2048 + (off) + 1024 + ssrc,  LVB(1,buf) + t*16);

  bf16x8 aq[4];
  {
    const u16* qp = qb + ((size_t)(b*2048 + q0 + l31))*512 + h*64 + hi*8;
    #pragma unroll
    for (int ks = 0; ks < 4; ++ks) aq[ks] = *(const bf16x8*)(qp + ks*16);
  }

  f32x16 acc[2] = {};
  float ps = 0.0f;

  STAGE(0, 0);
  __syncthreads();

  int cur = 0;
  for (int i = 0; i < 16; ++i) {
    if (i + 1 < 16) { STAGE(cur^1, (i+1)*64); }
    const char* lKc = LKB(half, cur);
    const char* lVc = LVB(half, cur);
    bf16x8 pb[4];
    #pragma unroll
    for (int n = 0; n < 2; ++n) {
      f32x16 s = {};
      #pragma unroll
      for (int ks = 0; ks < 4; ++ks) {
        bf16x8 kf = *(const bf16x8*)(lKc + swz(n*32 + l31, ks*32 + hi*16));
        s = MFMA32(kf, aq[ks], s);
      }
      mk_pb(s, ps, pb[2*n], pb[2*n+1]);
    }
    #pragma unroll
    for (int m = 0; m < 2; ++m)
      #pragma unroll
      for (int ks = 0; ks < 4; ++ks) {
        bf16x8 vf = *(const bf16x8*)(lVc + swz(m*32 + l31, ks*32 + hi*16));
        acc[m] = MFMA32(vf, pb[ks], acc[m]);
      }
    __syncthreads();
    cur ^= 1;
  }
#undef STAGE

  // ---- in-block combine: half-1 -> LDS (pitch 68 f32, region 2208 f32 per q-wave) ----
  ps += __shfl_xor(ps, 32, 64);
  float* cb = (float*)smem;
  if (half == 1) {
    float* dst = cb + qw * 2208;
    #pragma unroll
    for (int m = 0; m < 2; ++m)
      #pragma unroll
      for (int rq = 0; rq < 4; ++rq) {
        f32x4 v = {acc[m][rq*4], acc[m][rq*4+1], acc[m][rq*4+2], acc[m][rq*4+3]};
        *(f32x4*)(dst + l31*68 + m*32 + rq*8 + hi*4) = v;
      }
    if (hi == 0) dst[2176 + l31] = ps;
  }
  __syncthreads();
  if (half == 0) {
    const float* src = cb + qw * 2208;
    float inv = 1.0f / (ps + src[2176 + l31]);
    u16* obase = ob + ((size_t)(b*2048 + q0 + l31))*512 + h*64;
    const u16* qrb = qb + ((size_t)(b*2048 + q0 + l31))*512 + h*64;
    #pragma unroll
    for (int m = 0; m < 2; ++m)
      #pragma unroll
      for (int rq = 0; rq < 4; ++rq) {
        f32x4 other = *(const f32x4*)(src + l31*68 + m*32 + rq*8 + hi*4);
        u16x4 qr4 = *(const u16x4*)(qrb + m*32 + rq*8 + hi*4);
        u16x4 o4;
        #pragma unroll
        for (int e = 0; e < 4; ++e)
          o4[e] = f2bf((acc[m][rq*4 + e] + other[e])*inv + bf2f(qr4[e])*UNSCALE);
        *(u16x4*)(obase + m*32 + rq*8 + hi*4) = o4;
      }
  }
}

// ---------------- fused tail: LN0 (on-the-fly) -> Wo GEMM + ReLU + residual -> LN1 ------
__global__ __launch_bounds__(512) void tail_k(
    const u16* __restrict__ ob, const u16* __restrict__ Bt,
    const float* __restrict__ bo,
    const float* __restrict__ g0, const float* __restrict__ b0,
    const float* __restrict__ g1, const float* __restrict__ b1,
    float* __restrict__ out)
{
  __shared__ __align__(16) u16 lA[2][32*64];     // 4KB each
  __shared__ __align__(16) u16 lB[2][512*64];    // 64KB each
  __shared__ float mu0[32], rs0[32], mu1[32], rs1[32];
  __shared__ float ps1[32][8], ss1[32][8];

  int row0 = blockIdx.x * 32;
  int t = threadIdx.x, lane = t & 63, wid = t >> 6;
  int l15 = lane & 15, lg = lane >> 4;

  {
    int r = t >> 4, c0 = (t & 15) * 32;
    const u16* xp = ob + (size_t)(row0 + r)*512 + c0;
    float s = 0.0f, ss = 0.0f;
    #pragma unroll
    for (int j = 0; j < 4; ++j) {
      u16x8 v = *(const u16x8*)(xp + j*8);
      #pragma unroll
      for (int e = 0; e < 8; ++e) { float f = bf2f(v[e]); s += f; ss += f*f; }
    }
    #pragma unroll
    for (int m = 1; m < 16; m <<= 1) { s += __shfl_xor(s, m, 64); ss += __shfl_xor(ss, m, 64); }
    if ((t & 15) == 0) {
      float mu = s * (1.0f/512.0f);
      float var = ss * (1.0f/512.0f) - mu*mu;
      mu0[r] = mu; rs0[r] = rsqrtf(var + 1e-5f);
    }
  }
  __syncthreads();

  int ar = t >> 3, ak8 = t & 7;
  int br = t >> 3;
  int bsrc = ((t & 7) ^ (br & 7)) << 3;

  auto stageA = [&](int buf, int k0) {
    if (t < 256) {
      u16x8 x = *(const u16x8*)(ob + (size_t)(row0 + ar)*512 + k0 + ak8*8);
      f32x4 gv0 = *(const f32x4*)(g0 + k0 + ak8*8);
      f32x4 gv1 = *(const f32x4*)(g0 + k0 + ak8*8 + 4);
      f32x4 bv0 = *(const f32x4*)(b0 + k0 + ak8*8);
      f32x4 bv1 = *(const f32x4*)(b0 + k0 + ak8*8 + 4);
      float mu = mu0[ar], rs = rs0[ar];
      u16x8 h;
      #pragma unroll
      for (int j = 0; j < 4; ++j) {
        h[j]   = f2bf((bf2f(x[j])   - mu)*rs*gv0[j] + bv0[j]);
        h[j+4] = f2bf((bf2f(x[j+4]) - mu)*rs*gv1[j] + bv1[j]);
      }
      *(u16x8*)((char*)lA[buf] + swz(ar, ak8*16)) = h;
    }
  };

  #pragma unroll
  for (int i = 0; i < 8; ++i)
    gload16(Bt + (size_t)(br + i*64)*512 + bsrc, (char*)lB[0] + i*8192 + t*16);
  stageA(0, 0);
  __syncthreads();

  f32x4 acc[2][4] = {};
  int cur = 0;
  for (int k0 = 0; k0 < 512; k0 += 64) {
    if (k0 + 64 < 512) {
      #pragma unroll
      for (int i = 0; i < 8; ++i)
        gload16(Bt + (size_t)(br + i*64)*512 + k0 + 64 + bsrc, (char*)lB[cur^1] + i*8192 + t*16);
      stageA(cur^1, k0 + 64);
    }
    const char* lAc = (const char*)lA[cur];
    const char* lBc = (const char*)lB[cur];
    #pragma unroll
    for (int ks = 0; ks < 2; ++ks) {
      bf16x8 af[2], bfv[4];
      #pragma unroll
      for (int m = 0; m < 2; ++m)
        af[m] = *(const bf16x8*)(lAc + swz(m*16 + l15, ks*64 + lg*16));
      #pragma unroll
      for (int n = 0; n < 4; ++n)
        bfv[n] = *(const bf16x8*)(lBc + swz(wid*64 + n*16 + l15, ks*64 + lg*16));
      #pragma unroll
      for (int m = 0; m < 2; ++m)
        #pragma unroll
        for (int n = 0; n < 4; ++n)
          acc[m][n] = MFMA(af[m], bfv[n], acc[m][n]);
    }
    __syncthreads();
    cur ^= 1;
  }

  float Gv[2][4][4];
  float sp[2][4] = {}, ssp[2][4] = {};
  #pragma unroll
  for (int n = 0; n < 4; ++n) {
    int colg = wid*64 + n*16 + l15;
    float bov = bo[colg];
    float g0c = g0[colg], b0c = b0[colg];
    #pragma unroll
    for (int m = 0; m < 2; ++m) {
      #pragma unroll
      for (int rr = 0; rr < 4; ++rr) {
        int rit = m*16 + lg*4 + rr;
        float H = (bf2f(ob[(size_t)(row0 + rit)*512 + colg]) - mu0[rit])*rs0[rit]*g0c + b0c;
        float G = H + fmaxf(acc[m][n][rr] + bov, 0.0f);
        Gv[m][n][rr] = G;
        sp[m][rr] += G;
        ssp[m][rr] += G*G;
      }
    }
  }
  #pragma unroll
  for (int msk = 1; msk < 16; msk <<= 1)
    #pragma unroll
    for (int m = 0; m < 2; ++m)
      #pragma unroll
      for (int rr = 0; rr < 4; ++rr) {
        sp[m][rr]  += __shfl_xor(sp[m][rr],  msk, 64);
        ssp[m][rr] += __shfl_xor(ssp[m][rr], msk, 64);
      }
  if (l15 == 0) {
    #pragma unroll
    for (int m = 0; m < 2; ++m)
      #pragma unroll
      for (int rr = 0; rr < 4; ++rr) {
        int rit = m*16 + lg*4 + rr;
        ps1[rit][wid] = sp[m][rr];
        ss1[rit][wid] = ssp[m][rr];
      }
  }
  __syncthreads();
  if (t < 32) {
    float s = 0.0f, ss = 0.0f;
    #pragma unroll
    for (int w = 0; w < 8; ++w) { s += ps1[t][w]; ss += ss1[t][w]; }
    float mu = s * (1.0f/512.0f);
    float var = ss * (1.0f/512.0f) - mu*mu;
    mu1[t] = mu; rs1[t] = rsqrtf(var + 1e-5f);
  }
  __syncthreads();
  #pragma unroll
  for (int n = 0; n < 4; ++n) {
    int colg = wid*64 + n*16 + l15;
    float g1c = g1[colg], b1c = b1[colg];
    #pragma unroll
    for (int m = 0; m < 2; ++m)
      #pragma unroll
      for (int rr = 0; rr < 4; ++rr) {
        int rit = m*16 + lg*4 + rr;
        out[(size_t)(row0 + rit)*512 + colg] =
            (Gv[m][n][rr] - mu1[rit])*rs1[rit]*g1c + b1c;
      }
  }
}

extern "C" void kernel_launch(void* const* d_in, const int* in_sizes, int n_in,
                              void* d_out, int out_size, void* d_ws, size_t ws_size,
                              hipStream_t stream)
{
  const float* Q   = (const float*)d_in[0];
  const float* K   = (const float*)d_in[1];
  const float* Wq  = (const float*)d_in[2];
  const float* bq  = (const float*)d_in[3];
  const float* Wk  = (const float*)d_in[4];
  const float* bk  = (const float*)d_in[5];
  const float* Wv  = (const float*)d_in[6];
  const float* bv  = (const float*)d_in[7];
  const float* Wo  = (const float*)d_in[8];
  const float* bo  = (const float*)d_in[9];
  const float* g0  = (const float*)d_in[10];
  const float* b0  = (const float*)d_in[11];
  const float* g1  = (const float*)d_in[12];
  const float* b1  = (const float*)d_in[13];

  char* ws = (char*)d_ws;
  u16*   wt    = (u16*)(ws + 0);
  u16*   qbuf  = (u16*)(ws + (2u<<20));
  u16*   kbuf  = (u16*)(ws + (10u<<20));
  u16*   vt    = (u16*)(ws + (18u<<20));
  u16*   ob    = (u16*)(ws + (26u<<20));

  // 1. weight transpose+convert (Wq/bq scaled by 1/sqrt(512)*log2e)
  wprep_k<<<dim3(8, 8, 4), 256, 0, stream>>>(Wq, Wk, Wv, Wo, wt);
  // 2. projections: fused K+V (K staged once), V pre-transposed; XCD-grouped grid
  proj2_k<<<1024, 512, 0, stream>>>(Q, K, wt, bq, bk, bv, qbuf, kbuf, vt);
  // 3. attention, in-block KV-split + combine, XCD-swizzled grid -> ob (bf16, final)
  attn_k<<<512, 512, 0, stream>>>(qbuf, kbuf, vt, ob);
  // 4. fused tail: LN0 -> Wo GEMM + ReLU + residual -> LN1 -> out (fp32)
  tail_k<<<256, 512, 0, stream>>>(ob, wt + 3*262144, bo, g0, b0, g1, b1, (float*)d_out);
}